// Round 7
// baseline (789.160 us; speedup 1.0000x reference)
//
#include <hip/hip_runtime.h>

#define HDIM 2048
#define NBLK 512           // 4 waves/block, one output row per wave -> 2048 rows
#define NGRP 64            // two-level barrier: 64 groups of 8 blocks
#define GRP_STRIDE 16      // dwords between group counters (64 B apart)
#define BAR_WORDS (16 + NGRP * GRP_STRIDE)

struct Params {
    const float *xt, *h0, *feat, *number, *restr;
    const float *w_ih, *w_hh, *b_ih, *b_hh;
    const float *emb_w, *emb_b, *f1_w, *f1_b, *f2_w, *f2_b, *f3_w, *f3_b;
    const float *out_w, *out_b;
    unsigned *bar;                 // [0]=root cnt, [1]=root gen, [16+g*16]=grp g
    float *fd2, *hb0, *hb1, *out;
};

#define ALOAD(p)     __hip_atomic_load((p), __ATOMIC_RELAXED, __HIP_MEMORY_SCOPE_AGENT)
#define ASTORE(p, v) __hip_atomic_store((p), (v), __ATOMIC_RELAXED, __HIP_MEMORY_SCOPE_AGENT)

// ---------------------------------------------------------------------------
// Two-level software grid barrier. Happens-before chain for relaxed data
// atomics: writer ASTORE -> __syncthreads -> t0 acq_rel RMW -> (release seq)
// -> root gen release -> reader t0 acquire spin -> __syncthreads -> ALOAD.
// Graph-capturable (plain launch).
// ---------------------------------------------------------------------------
__device__ __forceinline__ void grid_barrier(unsigned* bar, int bid) {
    __syncthreads();
    if (threadIdx.x == 0) {
        unsigned* grp   = bar + 16 + (bid >> 3) * GRP_STRIDE;
        unsigned* rootc = bar;
        unsigned* rootg = bar + 1;
        const unsigned g = __hip_atomic_load(rootg, __ATOMIC_RELAXED,
                                             __HIP_MEMORY_SCOPE_AGENT);
        const unsigned a = __hip_atomic_fetch_add(grp, 1u, __ATOMIC_ACQ_REL,
                                                  __HIP_MEMORY_SCOPE_AGENT);
        bool last_grid = false;
        if (a == 7u) {   // last block of this group
            __hip_atomic_store(grp, 0u, __ATOMIC_RELAXED,
                               __HIP_MEMORY_SCOPE_AGENT);
            const unsigned r = __hip_atomic_fetch_add(rootc, 1u, __ATOMIC_ACQ_REL,
                                                      __HIP_MEMORY_SCOPE_AGENT);
            if (r == NGRP - 1u) {   // last block of the grid
                __hip_atomic_store(rootc, 0u, __ATOMIC_RELAXED,
                                   __HIP_MEMORY_SCOPE_AGENT);
                __hip_atomic_store(rootg, g + 1u, __ATOMIC_RELEASE,
                                   __HIP_MEMORY_SCOPE_AGENT);
                last_grid = true;
            }
        }
        if (!last_grid) {
            while (__hip_atomic_load(rootg, __ATOMIC_ACQUIRE,
                                     __HIP_MEMORY_SCOPE_AGENT) == g)
                __builtin_amdgcn_s_sleep(1);
        }
    }
    __syncthreads();
}

__global__ void init_kernel(unsigned* bar) {
    for (int i = threadIdx.x; i < BAR_WORDS; i += 256) bar[i] = 0u;
}

// ---------------------------------------------------------------------------
// Persistent fused kernel: MLP -> hid -> 7 GRU steps -> output head.
// One output row per wave (2048 waves). W[s+1] is register-prefetched before
// the barrier so HBM streams through the sync. h goes global->LDS once per
// block via agent atomics.
// ---------------------------------------------------------------------------
__global__ __launch_bounds__(256, 2) void fused_kernel(Params P) {
    const int tid   = threadIdx.x;
    const int bid   = blockIdx.x;
    const int wid   = tid >> 6;
    const int lane  = tid & 63;
    const int myrow = (bid << 2) + wid;          // 0..2047

    __shared__ __align__(16) float h_s[HDIM];    // 8 KB
    __shared__ float fd1[66];
    __shared__ float s_fd2[66];
    __shared__ float red[256];

    // ---- prefetch W[0] rows for this wave into registers (24 float4) ----
    float4 wreg[3][8];
    {
        const float4* Wb = (const float4*)P.w_hh;
#pragma unroll
        for (int g = 0; g < 3; ++g) {
            const float4* p = Wb + ((size_t)(g * HDIM + myrow) << 9);
#pragma unroll
            for (int k = 0; k < 8; ++k) wreg[g][k] = p[(k << 6) + lane];
        }
    }

    // ---- feature MLP: block 0 only (overlaps the W0 stream) ----
    if (bid == 0) {
        for (int o = wid; o < 66; o += 4) {
            const float* row = P.f1_w + o * 462;
            float s = 0.f;
            for (int k = lane; k < 462; k += 64) s = fmaf(row[k], P.feat[k], s);
#pragma unroll
            for (int off = 32; off; off >>= 1) s += __shfl_down(s, off);
            if (!lane) fd1[o] = s + P.f1_b[o];
        }
        __syncthreads();
        if (tid < 66) {
            float s = P.f2_b[tid];
            const float* row = P.f2_w + tid * 66;
            for (int k = 0; k < 66; ++k) s = fmaf(row[k], fd1[k], s);
            ASTORE(P.fd2 + tid, s);
        }
    }
    grid_barrier(P.bar, bid);

    // ---- hid: one wave per row. 66-dim fd2 sum: k=lane (0..63) for all
    // lanes + 2-lane tail for k=64,65 (lane<66 was the R4-R6 bug: lane<64
    // always, so terms 64,65 were dropped).
    {
        if (tid < 66) s_fd2[tid] = ALOAD(P.fd2 + tid);
        __syncthreads();
        float s = 0.f;
        if (lane < 34) s = P.emb_w[myrow * 34 + lane] * P.h0[lane];
        s = fmaf(P.f3_w[myrow * 66 + lane], s_fd2[lane], s);
        if (lane < 2)
            s = fmaf(P.f3_w[myrow * 66 + 64 + lane], s_fd2[64 + lane], s);
#pragma unroll
        for (int off = 32; off; off >>= 1) s += __shfl_down(s, off);
        if (!lane) ASTORE(P.hb0 + myrow, s + P.emb_b[myrow] + P.f3_b[myrow]);
    }
    grid_barrier(P.bar, bid);

    // ---- 7 GRU steps ----
    float* hb[2] = {P.hb0, P.hb1};
    for (int s = 0; s < 7; ++s) {
        const float* hin = hb[s & 1];
        float* hout      = hb[(s + 1) & 1];

        // h: global -> LDS once per block
#pragma unroll
        for (int i = 0; i < 8; ++i)
            h_s[tid + (i << 8)] = ALOAD(hin + tid + (i << 8));
        __syncthreads();

        // wave-uniform per-step scalars (needed only at the gates)
        const int boff = s * 3 * HDIM;
        const float xv  = P.xt[s];
        const float iwr = P.w_ih[boff + myrow];
        const float iwz = P.w_ih[boff + HDIM + myrow];
        const float iwn = P.w_ih[boff + 2 * HDIM + myrow];
        const float ibr = P.b_ih[boff + myrow];
        const float ibz = P.b_ih[boff + HDIM + myrow];
        const float ibn = P.b_ih[boff + 2 * HDIM + myrow];
        const float hbr = P.b_hh[boff + myrow];
        const float hbz = P.b_hh[boff + HDIM + myrow];
        const float hbn = P.b_hh[boff + 2 * HDIM + myrow];
        const float hself = h_s[myrow];

        // FMA: registers (weights) x LDS (h)
        const float4* h4p = (const float4*)h_s;
        float a0 = 0.f, a1 = 0.f, a2 = 0.f;
#pragma unroll
        for (int k = 0; k < 8; ++k) {
            const float4 h4 = h4p[(k << 6) + lane];
            a0 = fmaf(wreg[0][k].x, h4.x, fmaf(wreg[0][k].y, h4.y,
                 fmaf(wreg[0][k].z, h4.z, fmaf(wreg[0][k].w, h4.w, a0))));
            a1 = fmaf(wreg[1][k].x, h4.x, fmaf(wreg[1][k].y, h4.y,
                 fmaf(wreg[1][k].z, h4.z, fmaf(wreg[1][k].w, h4.w, a1))));
            a2 = fmaf(wreg[2][k].x, h4.x, fmaf(wreg[2][k].y, h4.y,
                 fmaf(wreg[2][k].z, h4.z, fmaf(wreg[2][k].w, h4.w, a2))));
        }

        // issue next-step weight prefetch NOW (wreg just consumed);
        // loads stay in flight through the reduce/gates/barrier
        if (s < 6) {
            const float4* Wb = (const float4*)(P.w_hh
                               + (size_t)(s + 1) * 3 * HDIM * HDIM);
#pragma unroll
            for (int g = 0; g < 3; ++g) {
                const float4* p = Wb + ((size_t)(g * HDIM + myrow) << 9);
#pragma unroll
                for (int k = 0; k < 8; ++k) wreg[g][k] = p[(k << 6) + lane];
            }
        }

        // wave reduction + gates
#pragma unroll
        for (int off = 32; off; off >>= 1) {
            a0 += __shfl_down(a0, off);
            a1 += __shfl_down(a1, off);
            a2 += __shfl_down(a2, off);
        }
        if (!lane) {
            const float gir = fmaf(xv, iwr, ibr);
            const float giz = fmaf(xv, iwz, ibz);
            const float gin = fmaf(xv, iwn, ibn);
            const float r = 1.f / (1.f + expf(-(gir + a0 + hbr)));
            const float z = 1.f / (1.f + expf(-(giz + a1 + hbz)));
            const float n = tanhf(fmaf(r, a2 + hbn, gin));
            ASTORE(hout + myrow, fmaf(z, hself - n, n));   // (1-z)*n + z*h
        }
        grid_barrier(P.bar, bid);
    }

    // ---- output head: block 0 ----
    if (bid == 0) {
        const float* h7 = hb[1];   // after 7 steps
        float s = 0.f;
        for (int k = tid; k < HDIM; k += 256)
            s = fmaf(P.out_w[k], ALOAD(h7 + k), s);
        red[tid] = s;
        __syncthreads();
#pragma unroll
        for (int off = 128; off; off >>= 1) {
            if (tid < off) red[tid] += red[tid + off];
            __syncthreads();
        }
        if (!tid)
            P.out[0] = red[0] + P.restr[0] * P.out_w[HDIM]
                     + P.number[0] * P.out_w[HDIM + 1] + P.out_b[0];
    }
}

// ---------------------------------------------------------------------------
extern "C" void kernel_launch(void* const* d_in, const int* in_sizes, int n_in,
                              void* d_out, int out_size, void* d_ws, size_t ws_size,
                              hipStream_t stream) {
    Params p;
    p.xt     = (const float*)d_in[0];
    p.h0     = (const float*)d_in[1];
    p.feat   = (const float*)d_in[2];
    p.number = (const float*)d_in[3];
    p.restr  = (const float*)d_in[4];
    p.w_ih   = (const float*)d_in[5];
    p.w_hh   = (const float*)d_in[6];
    p.b_ih   = (const float*)d_in[7];
    p.b_hh   = (const float*)d_in[8];
    p.emb_w  = (const float*)d_in[9];
    p.emb_b  = (const float*)d_in[10];
    p.f1_w   = (const float*)d_in[11];
    p.f1_b   = (const float*)d_in[12];
    p.f2_w   = (const float*)d_in[13];
    p.f2_b   = (const float*)d_in[14];
    p.f3_w   = (const float*)d_in[15];
    p.f3_b   = (const float*)d_in[16];
    p.out_w  = (const float*)d_in[17];
    p.out_b  = (const float*)d_in[18];

    float* ws = (float*)d_ws;
    p.bar = (unsigned*)d_ws;           // BAR_WORDS dwords
    p.fd2 = ws + 1056;                 // 66 floats
    p.hb0 = ws + 1280;                 // H floats
    p.hb1 = ws + 1280 + HDIM;          // H floats
    p.out = (float*)d_out;

    init_kernel<<<1, 256, 0, stream>>>(p.bar);
    fused_kernel<<<NBLK, 256, 0, stream>>>(p);
}

// Round 8
// 631.248 us; speedup vs baseline: 1.2502x; 1.2502x over previous
//
#include <hip/hip_runtime.h>

#define HDIM 2048
#define NBLK 512           // 4 waves/block, one output row per wave -> 2048 rows
#define NGRP 64            // two-level barrier: 64 groups of 8 blocks
#define GRP_STRIDE 32      // dwords between group lines (128 B apart)
#define BAR_WORDS (32 + NGRP * GRP_STRIDE)

struct Params {
    const float *xt, *h0, *feat, *number, *restr;
    const float *w_ih, *w_hh, *b_ih, *b_hh;
    const float *emb_w, *emb_b, *f1_w, *f1_b, *f2_w, *f2_b, *f3_w, *f3_b;
    const float *out_w, *out_b;
    unsigned *bar;       // [0]=root cnt, [1]=root gen, [32+g*32]=grp cnt, +1=go
    float *fd2, *hb0, *hb1, *out;
};

#define ARMW(p)      __hip_atomic_fetch_add((p), 1u, __ATOMIC_ACQ_REL, __HIP_MEMORY_SCOPE_AGENT)
#define ALOADR(p)    __hip_atomic_load((p), __ATOMIC_RELAXED, __HIP_MEMORY_SCOPE_AGENT)
#define ASTORER(p,v) __hip_atomic_store((p), (v), __ATOMIC_RELAXED, __HIP_MEMORY_SCOPE_AGENT)
#define ASTOREL(p,v) __hip_atomic_store((p), (v), __ATOMIC_RELEASE, __HIP_MEMORY_SCOPE_AGENT)

// ---------------------------------------------------------------------------
// Two-level software grid barrier, epoch-based. Data coherence: writer-side
// stores drain at the entry __syncthreads (vmcnt0), t0's __threadfence
// (release) writes back the XCD L2; reader-side t0 __threadfence after the
// relaxed spin invalidates stale lines (fence-fence sync with the release
// store). Spin is RELAXED + s_sleep(8): no cache ops, ~0.2us poll granularity,
// 8 pollers per group line / 64 on the root line (vs R7: 512 ACQUIRE pollers
// at 64cy on one line -> coherence-point saturation, 789us).
// ---------------------------------------------------------------------------
__device__ __forceinline__ void grid_barrier(unsigned* bar, int bid, unsigned e) {
    __syncthreads();
    if (threadIdx.x == 0) {
        __threadfence();                         // release: publish our stores
        unsigned* grpc  = bar + 32 + (bid >> 3) * GRP_STRIDE;
        unsigned* go    = grpc + 1;
        unsigned* rootc = bar;
        unsigned* rootg = bar + 1;
        const unsigned a = ARMW(grpc);
        if (a == 7u) {                           // group leader (8th arriver)
            ASTORER(grpc, 0u);                   // reset (ordered by release below)
            const unsigned r = ARMW(rootc);
            if (r == NGRP - 1u) {                // grid winner
                ASTORER(rootc, 0u);
                ASTOREL(rootg, e + 1u);
            } else {
                while (ALOADR(rootg) != e + 1u) __builtin_amdgcn_s_sleep(8);
                __threadfence();                 // acquire (sync w/ winner)
            }
            ASTOREL(go, e + 1u);                 // release to members
        } else {
            while (ALOADR(go) != e + 1u) __builtin_amdgcn_s_sleep(8);
        }
        __threadfence();                         // acquire: drop stale lines
    }
    __syncthreads();
}

__global__ void init_kernel(unsigned* bar) {
    for (int i = threadIdx.x; i < BAR_WORDS; i += 256) bar[i] = 0u;
}

// ---------------------------------------------------------------------------
// Persistent fused kernel: MLP -> hid -> 7 GRU steps -> output head.
// One output row per wave (2048 waves). W[s+1] register-prefetched right
// after wreg is consumed; h staged to LDS via float4 loads each step.
// ---------------------------------------------------------------------------
__global__ __launch_bounds__(256, 2) void fused_kernel(Params P) {
    const int tid   = threadIdx.x;
    const int bid   = blockIdx.x;
    const int wid   = tid >> 6;
    const int lane  = tid & 63;
    const int myrow = (bid << 2) + wid;          // 0..2047
    unsigned epoch  = 0;

    __shared__ __align__(16) float h_s[HDIM];    // 8 KB
    __shared__ float fd1[66];
    __shared__ float s_fd2[66];
    __shared__ float red[256];

    // ---- prefetch W[0] rows for this wave into registers (24 float4) ----
    float4 wreg[3][8];
    {
        const float4* Wb = (const float4*)P.w_hh;
#pragma unroll
        for (int g = 0; g < 3; ++g) {
            const float4* p = Wb + ((size_t)(g * HDIM + myrow) << 9);
#pragma unroll
            for (int k = 0; k < 8; ++k) wreg[g][k] = p[(k << 6) + lane];
        }
    }

    // ---- feature MLP: block 0 only (overlaps the W0 stream) ----
    if (bid == 0) {
        for (int o = wid; o < 66; o += 4) {
            const float* row = P.f1_w + o * 462;
            float s = 0.f;
            for (int k = lane; k < 462; k += 64) s = fmaf(row[k], P.feat[k], s);
#pragma unroll
            for (int off = 32; off; off >>= 1) s += __shfl_down(s, off);
            if (!lane) fd1[o] = s + P.f1_b[o];
        }
        __syncthreads();
        if (tid < 66) {
            float s = P.f2_b[tid];
            const float* row = P.f2_w + tid * 66;
            for (int k = 0; k < 66; ++k) s = fmaf(row[k], fd1[k], s);
            P.fd2[tid] = s;
        }
    }
    grid_barrier(P.bar, bid, epoch); ++epoch;

    // ---- hid: one wave per row; 66-dim fd2 sum = k=lane + 2-lane tail ----
    {
        if (tid < 66) s_fd2[tid] = P.fd2[tid];
        __syncthreads();
        float s = 0.f;
        if (lane < 34) s = P.emb_w[myrow * 34 + lane] * P.h0[lane];
        s = fmaf(P.f3_w[myrow * 66 + lane], s_fd2[lane], s);
        if (lane < 2)
            s = fmaf(P.f3_w[myrow * 66 + 64 + lane], s_fd2[64 + lane], s);
#pragma unroll
        for (int off = 32; off; off >>= 1) s += __shfl_down(s, off);
        if (!lane) P.hb0[myrow] = s + P.emb_b[myrow] + P.f3_b[myrow];
    }
    grid_barrier(P.bar, bid, epoch); ++epoch;

    // ---- 7 GRU steps ----
    float* hb[2] = {P.hb0, P.hb1};
    for (int s = 0; s < 7; ++s) {
        const float* hin = hb[s & 1];
        float* hout      = hb[(s + 1) & 1];

        // h: global -> LDS once per block, float4 (2 loads/thread)
        {
            const float4* h4g = (const float4*)hin;
            float4* h4s = (float4*)h_s;
            h4s[tid]       = h4g[tid];
            h4s[tid + 256] = h4g[tid + 256];
        }
        __syncthreads();

        // wave-uniform per-step scalars (used only at the gates)
        const int boff = s * 3 * HDIM;
        const float xv  = P.xt[s];
        const float iwr = P.w_ih[boff + myrow];
        const float iwz = P.w_ih[boff + HDIM + myrow];
        const float iwn = P.w_ih[boff + 2 * HDIM + myrow];
        const float ibr = P.b_ih[boff + myrow];
        const float ibz = P.b_ih[boff + HDIM + myrow];
        const float ibn = P.b_ih[boff + 2 * HDIM + myrow];
        const float hbr = P.b_hh[boff + myrow];
        const float hbz = P.b_hh[boff + HDIM + myrow];
        const float hbn = P.b_hh[boff + 2 * HDIM + myrow];
        const float hself = h_s[myrow];

        // FMA: registers (weights) x LDS (h)
        const float4* h4p = (const float4*)h_s;
        float a0 = 0.f, a1 = 0.f, a2 = 0.f;
#pragma unroll
        for (int k = 0; k < 8; ++k) {
            const float4 h4 = h4p[(k << 6) + lane];
            a0 = fmaf(wreg[0][k].x, h4.x, fmaf(wreg[0][k].y, h4.y,
                 fmaf(wreg[0][k].z, h4.z, fmaf(wreg[0][k].w, h4.w, a0))));
            a1 = fmaf(wreg[1][k].x, h4.x, fmaf(wreg[1][k].y, h4.y,
                 fmaf(wreg[1][k].z, h4.z, fmaf(wreg[1][k].w, h4.w, a1))));
            a2 = fmaf(wreg[2][k].x, h4.x, fmaf(wreg[2][k].y, h4.y,
                 fmaf(wreg[2][k].z, h4.z, fmaf(wreg[2][k].w, h4.w, a2))));
        }

        // issue next-step weight prefetch NOW (wreg just consumed); the loads
        // drain at the barrier-entry syncthreads, overlapping reduce/gates.
        if (s < 6) {
            const float4* Wb = (const float4*)(P.w_hh
                               + (size_t)(s + 1) * 3 * HDIM * HDIM);
#pragma unroll
            for (int g = 0; g < 3; ++g) {
                const float4* p = Wb + ((size_t)(g * HDIM + myrow) << 9);
#pragma unroll
                for (int k = 0; k < 8; ++k) wreg[g][k] = p[(k << 6) + lane];
            }
        }

        // wave reduction + gates
#pragma unroll
        for (int off = 32; off; off >>= 1) {
            a0 += __shfl_down(a0, off);
            a1 += __shfl_down(a1, off);
            a2 += __shfl_down(a2, off);
        }
        if (!lane) {
            const float gir = fmaf(xv, iwr, ibr);
            const float giz = fmaf(xv, iwz, ibz);
            const float gin = fmaf(xv, iwn, ibn);
            const float r = 1.f / (1.f + expf(-(gir + a0 + hbr)));
            const float z = 1.f / (1.f + expf(-(giz + a1 + hbz)));
            const float n = tanhf(fmaf(r, a2 + hbn, gin));
            hout[myrow] = fmaf(z, hself - n, n);   // (1-z)*n + z*h
        }
        grid_barrier(P.bar, bid, epoch); ++epoch;
    }

    // ---- output head: block 0 ----
    if (bid == 0) {
        const float* h7 = hb[1];   // after 7 steps
        float s = 0.f;
        for (int k = tid; k < HDIM; k += 256) s = fmaf(P.out_w[k], h7[k], s);
        red[tid] = s;
        __syncthreads();
#pragma unroll
        for (int off = 128; off; off >>= 1) {
            if (tid < off) red[tid] += red[tid + off];
            __syncthreads();
        }
        if (!tid)
            P.out[0] = red[0] + P.restr[0] * P.out_w[HDIM]
                     + P.number[0] * P.out_w[HDIM + 1] + P.out_b[0];
    }
}

// ---------------------------------------------------------------------------
extern "C" void kernel_launch(void* const* d_in, const int* in_sizes, int n_in,
                              void* d_out, int out_size, void* d_ws, size_t ws_size,
                              hipStream_t stream) {
    Params p;
    p.xt     = (const float*)d_in[0];
    p.h0     = (const float*)d_in[1];
    p.feat   = (const float*)d_in[2];
    p.number = (const float*)d_in[3];
    p.restr  = (const float*)d_in[4];
    p.w_ih   = (const float*)d_in[5];
    p.w_hh   = (const float*)d_in[6];
    p.b_ih   = (const float*)d_in[7];
    p.b_hh   = (const float*)d_in[8];
    p.emb_w  = (const float*)d_in[9];
    p.emb_b  = (const float*)d_in[10];
    p.f1_w   = (const float*)d_in[11];
    p.f1_b   = (const float*)d_in[12];
    p.f2_w   = (const float*)d_in[13];
    p.f2_b   = (const float*)d_in[14];
    p.f3_w   = (const float*)d_in[15];
    p.f3_b   = (const float*)d_in[16];
    p.out_w  = (const float*)d_in[17];
    p.out_b  = (const float*)d_in[18];

    float* ws = (float*)d_ws;
    p.bar = (unsigned*)d_ws;           // BAR_WORDS dwords
    p.fd2 = ws + 2080;                 // 66 floats
    p.hb0 = ws + 2304;                 // H floats
    p.hb1 = ws + 2304 + HDIM;          // H floats
    p.out = (float*)d_out;

    init_kernel<<<1, 256, 0, stream>>>(p.bar);
    fused_kernel<<<NBLK, 256, 0, stream>>>(p);
}

// Round 9
// 191.998 us; speedup vs baseline: 4.1103x; 3.2878x over previous
//
#include <hip/hip_runtime.h>

#define HDIM 2048

// ---------------------------------------------------------------------------
// Feature MLP: feat(462) -> fd1(66) -> fd2(66). One block, 256 threads.
// ---------------------------------------------------------------------------
__global__ __launch_bounds__(256) void mlp_kernel(
    const float* __restrict__ feat,      // 462
    const float* __restrict__ f1_w,      // (66,462)
    const float* __restrict__ f1_b,      // 66
    const float* __restrict__ f2_w,      // (66,66)
    const float* __restrict__ f2_b,      // 66
    float* __restrict__ fd2_out)         // 66
{
    __shared__ float fd1[66];
    const int wid  = threadIdx.x >> 6;
    const int lane = threadIdx.x & 63;
    for (int o = wid; o < 66; o += 4) {
        const float* row = f1_w + o * 462;
        float s = 0.f;
        for (int k = lane; k < 462; k += 64) s = fmaf(row[k], feat[k], s);
#pragma unroll
        for (int off = 32; off; off >>= 1) s += __shfl_down(s, off);
        if (!lane) fd1[o] = s + f1_b[o];
    }
    __syncthreads();
    const int t = threadIdx.x;
    if (t < 66) {
        float s = f2_b[t];
        const float* row = f2_w + t * 66;
        for (int k = 0; k < 66; ++k) s = fmaf(row[k], fd1[k], s);
        fd2_out[t] = s;
    }
}

// ---------------------------------------------------------------------------
// hid = h0 @ emb_w.T + emb_b + fd2 @ f3_w.T + f3_b.  512 blocks, one row per
// wave. Also L3-prefetches W[0] (one dword per 64B sector, 6 loads/thread,
// kept alive by empty asm) so step 0's demand reads hit L3, not cold HBM.
// ---------------------------------------------------------------------------
__global__ __launch_bounds__(256) void hid_kernel(
    const float* __restrict__ h0,        // 34
    const float* __restrict__ emb_w,     // (H,34)
    const float* __restrict__ emb_b,     // H
    const float* __restrict__ f3_w,      // (H,66)
    const float* __restrict__ f3_b,      // H
    const float* __restrict__ fd2,       // 66
    const float* __restrict__ w0,        // (3H,H): W[0] for prefetch
    float* __restrict__ h_out)           // H
{
    const int wid   = threadIdx.x >> 6;
    const int lane  = threadIdx.x & 63;
    const int myrow = (blockIdx.x << 2) + wid;   // 0..2047

    // ---- W[0] L3-prefetch: rows myrow, H+myrow, 2H+myrow ----
    const int o = lane << 5;                     // lane*32 floats = 128 B
    const float* n0 = w0 + (size_t)myrow * HDIM;
    const float* n1 = w0 + (size_t)(HDIM + myrow) * HDIM;
    const float* n2 = w0 + (size_t)(2 * HDIM + myrow) * HDIM;
    const float p0 = n0[o], p1 = n0[o + 16];
    const float p2 = n1[o], p3 = n1[o + 16];
    const float p4 = n2[o], p5 = n2[o + 16];

    // ---- hid row: 34-dim emb + 66-dim fd2 (k=lane + 2-lane tail) ----
    float s = 0.f;
    if (lane < 34) s = emb_w[myrow * 34 + lane] * h0[lane];
    s = fmaf(f3_w[myrow * 66 + lane], fd2[lane], s);
    if (lane < 2) s = fmaf(f3_w[myrow * 66 + 64 + lane], fd2[64 + lane], s);
#pragma unroll
    for (int off = 32; off; off >>= 1) s += __shfl_down(s, off);
    if (!lane) h_out[myrow] = s + emb_b[myrow] + f3_b[myrow];

    // keep prefetch loads alive (rule #17: anti-DCE)
    asm volatile("" :: "v"(p0), "v"(p1), "v"(p2), "v"(p3), "v"(p4), "v"(p5));
}

// ---------------------------------------------------------------------------
// One GRU step (R2-validated core). One wave per output row j; three
// H-length dots over rows j, H+j, 2H+j; h float4s reused for all 3 rows.
// Plus: L3-prefetch of W[s+1]'s same rows (6 dword loads/thread) so the
// next step's demand reads hit L3; HBM streams continuously across steps.
// ---------------------------------------------------------------------------
__global__ __launch_bounds__(256) void gru_step_kernel(
    const float* __restrict__ w_hh,      // (3H,H)   [offset to step s]
    const float* __restrict__ w_nx,      // (3H,H)   [step s+1, for prefetch]
    const int do_pf,
    const float* __restrict__ w_ih,      // (3H)     [col 0; offset]
    const float* __restrict__ b_ih,      // (3H)
    const float* __restrict__ b_hh,      // (3H)
    const float* __restrict__ xt,        // (7)
    const int step,
    const float* __restrict__ h_in,      // H
    float* __restrict__ h_out)           // H
{
    const int wave = (blockIdx.x * blockDim.x + threadIdx.x) >> 6;  // 0..H-1
    const int lane = threadIdx.x & 63;
    const int j = wave;

    // ---- issue next-step W prefetch early (HBM starts streaming now) ----
    float p0 = 0.f, p1 = 0.f, p2 = 0.f, p3 = 0.f, p4 = 0.f, p5 = 0.f;
    if (do_pf) {
        const int o = lane << 5;                 // 128 B stride
        const float* n0 = w_nx + (size_t)j * HDIM;
        const float* n1 = w_nx + (size_t)(HDIM + j) * HDIM;
        const float* n2 = w_nx + (size_t)(2 * HDIM + j) * HDIM;
        p0 = n0[o]; p1 = n0[o + 16];
        p2 = n1[o]; p3 = n1[o + 16];
        p4 = n2[o]; p5 = n2[o + 16];
    }

    const float4* hv4 = (const float4*)h_in;
    const float4* wr  = (const float4*)(w_hh + (size_t)j * HDIM);
    const float4* wz  = (const float4*)(w_hh + (size_t)(HDIM + j) * HDIM);
    const float4* wn  = (const float4*)(w_hh + (size_t)(2 * HDIM + j) * HDIM);

    float sr = 0.f, sz = 0.f, sn = 0.f;
#pragma unroll
    for (int i = 0; i < 8; ++i) {
        const int idx = i * 64 + lane;           // float4 index, 512 per row
        const float4 h4 = hv4[idx];
        const float4 a  = wr[idx];
        const float4 b  = wz[idx];
        const float4 c  = wn[idx];
        sr = fmaf(a.x, h4.x, fmaf(a.y, h4.y, fmaf(a.z, h4.z, fmaf(a.w, h4.w, sr))));
        sz = fmaf(b.x, h4.x, fmaf(b.y, h4.y, fmaf(b.z, h4.z, fmaf(b.w, h4.w, sz))));
        sn = fmaf(c.x, h4.x, fmaf(c.y, h4.y, fmaf(c.z, h4.z, fmaf(c.w, h4.w, sn))));
    }
#pragma unroll
    for (int off = 32; off; off >>= 1) {
        sr += __shfl_down(sr, off);
        sz += __shfl_down(sz, off);
        sn += __shfl_down(sn, off);
    }

    if (!lane) {
        const float x = xt[step];
        const float gir = fmaf(x, w_ih[j],            b_ih[j]);
        const float giz = fmaf(x, w_ih[HDIM + j],     b_ih[HDIM + j]);
        const float gin = fmaf(x, w_ih[2 * HDIM + j], b_ih[2 * HDIM + j]);
        const float ghr = sr + b_hh[j];
        const float ghz = sz + b_hh[HDIM + j];
        const float ghn = sn + b_hh[2 * HDIM + j];
        const float r = 1.f / (1.f + expf(-(gir + ghr)));
        const float z = 1.f / (1.f + expf(-(giz + ghz)));
        const float n = tanhf(fmaf(r, ghn, gin));
        h_out[j] = fmaf(z, h_in[j] - n, n);   // (1-z)*n + z*h
    }

    // keep prefetch loads alive (anti-DCE); forces vmcnt drain in-kernel
    if (do_pf)
        asm volatile("" :: "v"(p0), "v"(p1), "v"(p2), "v"(p3), "v"(p4), "v"(p5));
}

// ---------------------------------------------------------------------------
// out = h7 . out_w[0:H] + restrict*out_w[H] + number*out_w[H+1] + out_b
// ---------------------------------------------------------------------------
__global__ __launch_bounds__(256) void out_kernel(
    const float* __restrict__ h7,        // H
    const float* __restrict__ out_w,     // H+2
    const float* __restrict__ out_b,     // 1
    const float* __restrict__ restr,     // 1
    const float* __restrict__ number,    // 1
    float* __restrict__ out)             // 1 (fp32)
{
    __shared__ float red[256];
    const int t = threadIdx.x;
    float s = 0.f;
    for (int k = t; k < HDIM; k += 256) s = fmaf(out_w[k], h7[k], s);
    red[t] = s;
    __syncthreads();
#pragma unroll
    for (int off = 128; off; off >>= 1) {
        if (t < off) red[t] += red[t + off];
        __syncthreads();
    }
    if (!t) {
        out[0] = red[0] + restr[0] * out_w[HDIM] + number[0] * out_w[HDIM + 1]
               + out_b[0];
    }
}

// ---------------------------------------------------------------------------
extern "C" void kernel_launch(void* const* d_in, const int* in_sizes, int n_in,
                              void* d_out, int out_size, void* d_ws, size_t ws_size,
                              hipStream_t stream) {
    const float* xt     = (const float*)d_in[0];
    const float* h0     = (const float*)d_in[1];
    const float* feat   = (const float*)d_in[2];
    const float* number = (const float*)d_in[3];
    const float* restr  = (const float*)d_in[4];
    const float* w_ih   = (const float*)d_in[5];
    const float* w_hh   = (const float*)d_in[6];
    const float* b_ih   = (const float*)d_in[7];
    const float* b_hh   = (const float*)d_in[8];
    const float* emb_w  = (const float*)d_in[9];
    const float* emb_b  = (const float*)d_in[10];
    const float* f1_w   = (const float*)d_in[11];
    const float* f1_b   = (const float*)d_in[12];
    const float* f2_w   = (const float*)d_in[13];
    const float* f2_b   = (const float*)d_in[14];
    const float* f3_w   = (const float*)d_in[15];
    const float* f3_b   = (const float*)d_in[16];
    const float* out_w  = (const float*)d_in[17];
    const float* out_b  = (const float*)d_in[18];

    float* ws    = (float*)d_ws;
    float* fd2   = ws;              // 66 floats
    float* hbuf0 = ws + 256;        // H floats
    float* hbuf1 = ws + 256 + HDIM; // H floats

    mlp_kernel<<<1, 256, 0, stream>>>(feat, f1_w, f1_b, f2_w, f2_b, fd2);
    hid_kernel<<<512, 256, 0, stream>>>(h0, emb_w, emb_b, f3_w, f3_b, fd2,
                                        w_hh /* W[0] prefetch */, hbuf0);

    float* bufs[2] = {hbuf0, hbuf1};
    for (int s = 0; s < 7; ++s) {
        const int pf = (s < 6) ? 1 : 0;
        const float* wnx = w_hh + (size_t)(pf ? (s + 1) : s) * 3 * HDIM * HDIM;
        gru_step_kernel<<<(HDIM * 64) / 256, 256, 0, stream>>>(
            w_hh + (size_t)s * 3 * HDIM * HDIM,
            wnx, pf,
            w_ih + (size_t)s * 3 * HDIM,
            b_ih + (size_t)s * 3 * HDIM,
            b_hh + (size_t)s * 3 * HDIM,
            xt, s, bufs[s & 1], bufs[(s + 1) & 1]);
    }

    out_kernel<<<1, 256, 0, stream>>>(bufs[1], out_w, out_b, restr, number,
                                      (float*)d_out);
}

// Round 10
// 157.034 us; speedup vs baseline: 5.0254x; 1.2226x over previous
//
#include <hip/hip_runtime.h>

#define HDIM 2048

// global -> LDS direct copy, 16 B per lane, fire-and-forget (vmcnt).
__device__ __forceinline__ void load_lds16(const float* g, float* l) {
    typedef const __attribute__((address_space(1))) void* gvp;
    typedef __attribute__((address_space(3))) void* lvp;
    __builtin_amdgcn_global_load_lds((gvp)(const void*)g, (lvp)(void*)l,
                                     16, 0, 0);
}

// ---------------------------------------------------------------------------
// Feature MLP: feat(462) -> fd1(66) -> fd2(66). One block.
// ---------------------------------------------------------------------------
__global__ __launch_bounds__(256) void mlp_kernel(
    const float* __restrict__ feat,      // 462
    const float* __restrict__ f1_w,      // (66,462)
    const float* __restrict__ f1_b,      // 66
    const float* __restrict__ f2_w,      // (66,66)
    const float* __restrict__ f2_b,      // 66
    float* __restrict__ fd2_out)         // 66
{
    __shared__ float fd1[66];
    const int wid  = threadIdx.x >> 6;
    const int lane = threadIdx.x & 63;
    for (int o = wid; o < 66; o += 4) {
        const float* row = f1_w + o * 462;
        float s = 0.f;
        for (int k = lane; k < 462; k += 64) s = fmaf(row[k], feat[k], s);
#pragma unroll
        for (int off = 32; off; off >>= 1) s += __shfl_down(s, off);
        if (!lane) fd1[o] = s + f1_b[o];
    }
    __syncthreads();
    const int t = threadIdx.x;
    if (t < 66) {
        float s = f2_b[t];
        const float* row = f2_w + t * 66;
        for (int k = 0; k < 66; ++k) s = fmaf(row[k], fd1[k], s);
        fd2_out[t] = s;
    }
}

// ---------------------------------------------------------------------------
// hid = h0 @ emb_w.T + emb_b + fd2 @ f3_w.T + f3_b. 512 blocks, 1 row/wave.
// (R9-validated: 66-dim sum = k=lane for all lanes + 2-lane tail for 64,65.)
// ---------------------------------------------------------------------------
__global__ __launch_bounds__(256) void hid_kernel(
    const float* __restrict__ h0,        // 34
    const float* __restrict__ emb_w,     // (H,34)
    const float* __restrict__ emb_b,     // H
    const float* __restrict__ f3_w,      // (H,66)
    const float* __restrict__ f3_b,      // H
    const float* __restrict__ fd2,       // 66
    float* __restrict__ h_out)           // H
{
    const int wid   = threadIdx.x >> 6;
    const int lane  = threadIdx.x & 63;
    const int myrow = (blockIdx.x << 2) + wid;   // 0..2047

    float s = 0.f;
    if (lane < 34) s = emb_w[myrow * 34 + lane] * h0[lane];
    s = fmaf(f3_w[myrow * 66 + lane], fd2[lane], s);
    if (lane < 2) s = fmaf(f3_w[myrow * 66 + 64 + lane], fd2[64 + lane], s);
#pragma unroll
    for (int off = 32; off; off >>= 1) s += __shfl_down(s, off);
    if (!lane) h_out[myrow] = s + emb_b[myrow] + f3_b[myrow];
}

// ---------------------------------------------------------------------------
// One GRU step. ONE BLOCK PER OUTPUT ROW j (2048 blocks, 4 waves each).
// Stage rows {j, H+j, 2H+j} of w_hh (24 KB) into LDS via global_load_lds:
// fire-and-forget, no VGPR round-trip -> ~24 KB in flight per block, 6
// blocks/CU resident (LDS-capped) -> ~144 KB in flight per CU, enough to
// saturate HBM against ~900ns latency (R2's float4 path: only ~4 KB/CU ->
// 4 TB/s ceiling, the measured limit).
// ---------------------------------------------------------------------------
__global__ __launch_bounds__(256) void gru_step_kernel(
    const float* __restrict__ w_hh,      // (3H,H)   [offset to step s]
    const float* __restrict__ w_ih,      // (3H)     [col 0; offset]
    const float* __restrict__ b_ih,      // (3H)
    const float* __restrict__ b_hh,      // (3H)
    const float* __restrict__ xt,        // (7)
    const int step,
    const float* __restrict__ h_in,      // H
    float* __restrict__ h_out)           // H
{
    __shared__ __align__(16) float lds[3][HDIM];   // 24 KB
    __shared__ float part[4][3];

    const int tid  = threadIdx.x;
    const int wid  = tid >> 6;
    const int lane = tid & 63;
    const int j    = blockIdx.x;

    // early per-row scalars (thread 0 only; loads issue now, used at the end)
    float xv = 0.f, iwr = 0.f, iwz = 0.f, iwn = 0.f;
    float ibr = 0.f, ibz = 0.f, ibn = 0.f, hbr = 0.f, hbz = 0.f, hbn = 0.f;
    float hself = 0.f;
    if (tid == 0) {
        xv  = xt[step];
        iwr = w_ih[j]; iwz = w_ih[HDIM + j]; iwn = w_ih[2 * HDIM + j];
        ibr = b_ih[j]; ibz = b_ih[HDIM + j]; ibn = b_ih[2 * HDIM + j];
        hbr = b_hh[j]; hbz = b_hh[HDIM + j]; hbn = b_hh[2 * HDIM + j];
        hself = h_in[j];
    }

    // ---- stage 3 x 8 KB weight rows into LDS (6 instr/thread, in flight) ----
    // row g = 8 segments of 1 KB; wave w stages segments {2w, 2w+1}
#pragma unroll
    for (int g = 0; g < 3; ++g) {
        const float* rowg = w_hh + (size_t)(g * HDIM + j) * HDIM;
#pragma unroll
        for (int i = 0; i < 2; ++i) {
            const int seg = (wid << 1) + i;                  // 0..7
            const int o   = (seg << 8) + (lane << 2);        // float index
            load_lds16(rowg + o, &lds[g][o]);
        }
    }
    __syncthreads();   // drains vmcnt(0) (global_load_lds) + barrier

    // ---- compute: thread t covers k = [4t,4t+4) and [1024+4t, 1024+4t+4) ----
    // (consecutive lanes read consecutive 16 B: conflict-free ds_read_b128,
    //  fully-coalesced h float4 reads)
    const float4* hv = (const float4*)h_in;
    const float4 hA = hv[tid];
    const float4 hB = hv[tid + 256];
    const float4* l0 = (const float4*)lds[0];
    const float4* l1 = (const float4*)lds[1];
    const float4* l2 = (const float4*)lds[2];

    float s0, s1, s2;
    {
        const float4 a = l0[tid], b = l0[tid + 256];
        s0 = a.x * hA.x + a.y * hA.y + a.z * hA.z + a.w * hA.w
           + b.x * hB.x + b.y * hB.y + b.z * hB.z + b.w * hB.w;
    }
    {
        const float4 a = l1[tid], b = l1[tid + 256];
        s1 = a.x * hA.x + a.y * hA.y + a.z * hA.z + a.w * hA.w
           + b.x * hB.x + b.y * hB.y + b.z * hB.z + b.w * hB.w;
    }
    {
        const float4 a = l2[tid], b = l2[tid + 256];
        s2 = a.x * hA.x + a.y * hA.y + a.z * hA.z + a.w * hA.w
           + b.x * hB.x + b.y * hB.y + b.z * hB.z + b.w * hB.w;
    }

    // ---- two-level reduction: wave shuffle, then 4 wave-partials ----
#pragma unroll
    for (int off = 32; off; off >>= 1) {
        s0 += __shfl_down(s0, off);
        s1 += __shfl_down(s1, off);
        s2 += __shfl_down(s2, off);
    }
    if (!lane) {
        part[wid][0] = s0; part[wid][1] = s1; part[wid][2] = s2;
    }
    __syncthreads();

    if (tid == 0) {
        const float a0 = part[0][0] + part[1][0] + part[2][0] + part[3][0];
        const float a1 = part[0][1] + part[1][1] + part[2][1] + part[3][1];
        const float a2 = part[0][2] + part[1][2] + part[2][2] + part[3][2];
        const float gir = fmaf(xv, iwr, ibr);
        const float giz = fmaf(xv, iwz, ibz);
        const float gin = fmaf(xv, iwn, ibn);
        const float r = 1.f / (1.f + expf(-(gir + a0 + hbr)));
        const float z = 1.f / (1.f + expf(-(giz + a1 + hbz)));
        const float n = tanhf(fmaf(r, a2 + hbn, gin));
        h_out[j] = fmaf(z, hself - n, n);   // (1-z)*n + z*h
    }
}

// ---------------------------------------------------------------------------
// out = h7 . out_w[0:H] + restrict*out_w[H] + number*out_w[H+1] + out_b
// ---------------------------------------------------------------------------
__global__ __launch_bounds__(256) void out_kernel(
    const float* __restrict__ h7,        // H
    const float* __restrict__ out_w,     // H+2
    const float* __restrict__ out_b,     // 1
    const float* __restrict__ restr,     // 1
    const float* __restrict__ number,    // 1
    float* __restrict__ out)             // 1 (fp32)
{
    __shared__ float red[256];
    const int t = threadIdx.x;
    float s = 0.f;
    for (int k = t; k < HDIM; k += 256) s = fmaf(out_w[k], h7[k], s);
    red[t] = s;
    __syncthreads();
#pragma unroll
    for (int off = 128; off; off >>= 1) {
        if (t < off) red[t] += red[t + off];
        __syncthreads();
    }
    if (!t) {
        out[0] = red[0] + restr[0] * out_w[HDIM] + number[0] * out_w[HDIM + 1]
               + out_b[0];
    }
}

// ---------------------------------------------------------------------------
extern "C" void kernel_launch(void* const* d_in, const int* in_sizes, int n_in,
                              void* d_out, int out_size, void* d_ws, size_t ws_size,
                              hipStream_t stream) {
    const float* xt     = (const float*)d_in[0];
    const float* h0     = (const float*)d_in[1];
    const float* feat   = (const float*)d_in[2];
    const float* number = (const float*)d_in[3];
    const float* restr  = (const float*)d_in[4];
    const float* w_ih   = (const float*)d_in[5];
    const float* w_hh   = (const float*)d_in[6];
    const float* b_ih   = (const float*)d_in[7];
    const float* b_hh   = (const float*)d_in[8];
    const float* emb_w  = (const float*)d_in[9];
    const float* emb_b  = (const float*)d_in[10];
    const float* f1_w   = (const float*)d_in[11];
    const float* f1_b   = (const float*)d_in[12];
    const float* f2_w   = (const float*)d_in[13];
    const float* f2_b   = (const float*)d_in[14];
    const float* f3_w   = (const float*)d_in[15];
    const float* f3_b   = (const float*)d_in[16];
    const float* out_w  = (const float*)d_in[17];
    const float* out_b  = (const float*)d_in[18];

    float* ws    = (float*)d_ws;
    float* fd2   = ws;              // 66 floats
    float* hbuf0 = ws + 256;        // H floats
    float* hbuf1 = ws + 256 + HDIM; // H floats

    mlp_kernel<<<1, 256, 0, stream>>>(feat, f1_w, f1_b, f2_w, f2_b, fd2);
    hid_kernel<<<512, 256, 0, stream>>>(h0, emb_w, emb_b, f3_w, f3_b, fd2,
                                        hbuf0);

    float* bufs[2] = {hbuf0, hbuf1};
    for (int s = 0; s < 7; ++s) {
        gru_step_kernel<<<HDIM, 256, 0, stream>>>(
            w_hh + (size_t)s * 3 * HDIM * HDIM,
            w_ih + (size_t)s * 3 * HDIM,
            b_ih + (size_t)s * 3 * HDIM,
            b_hh + (size_t)s * 3 * HDIM,
            xt, s, bufs[s & 1], bufs[(s + 1) & 1]);
    }

    out_kernel<<<1, 256, 0, stream>>>(bufs[1], out_w, out_b, restr, number,
                                      (float*)d_out);
}